// Round 19
// baseline (4829.124 us; speedup 1.0000x reference)
//
#include <hip/hip_runtime.h>
#include <hip/hip_cooperative_groups.h>

#define NN 100000
#define NE 3200000
#define DIN 512
#define DHID 256
#define DOUT 64
#define KPROP 10
#define MLP_BLKS ((NN + 63) / 64)        // 1563
#define CNT_BLKS ((NE / 4 + 255) / 256)  // 3125
#define FILL_BLKS ((NE / 4 + 255) / 256) // 3125
#define PROP_BLKS 1536                   // 6 blocks/CU co-resident (coop)
#define NCHUNK ((25000 + PROP_BLKS - 1) / PROP_BLKS)  // 17

typedef _Float16 f16;
typedef _Float16 f16x8 __attribute__((ext_vector_type(8)));
typedef _Float16 f16x4 __attribute__((ext_vector_type(4)));
typedef float f32x4 __attribute__((ext_vector_type(4)));

namespace cg = cooperative_groups;

// ---------------- zero + edge-layout probe (fused) ----------------
__global__ void zero_detect(int* __restrict__ cnt, const int* __restrict__ ei,
                            int* __restrict__ flag) {
  int g = blockIdx.x * blockDim.x + threadIdx.x;
  if (g < NN) cnt[g] = 0;
  if (blockIdx.x == 0 && threadIdx.x < 64) {
    int lane = threadIdx.x;
    int ok = 1;
    for (int i = lane; i < 512; i += 64)
      if (ei[2 * i + 1] != 0) ok = 0;
    ok = __all(ok);
    if (lane == 0) *flag = ok;
  }
}

// ---------------- weight transpose + fp16 convert ----------------
__global__ void cvt_weights(const float* __restrict__ W1, const float* __restrict__ W2,
                            f16* __restrict__ W1t, f16* __restrict__ W2t) {
  int g = blockIdx.x * 256 + threadIdx.x;
  if (g < DIN * DHID) {
    int k = g >> 8, n = g & 255;
    W1t[(size_t)n * DIN + k] = (f16)W1[g];
  }
  if (g < DHID * DOUT) {
    int k = g >> 6, n = g & 63;
    W2t[(size_t)n * DHID + k] = (f16)W2[g];
  }
}

// ---------------- FUSED: mlp (blocks 0..1562) + count_deg (rest) ---------
// (r18 measured: 250us vs 288 sequential — overlap of atomic-unit-bound
// count with latency-bound mlp.)
__global__ __launch_bounds__(256) void count_mlp(
    const int* __restrict__ ei, const int* __restrict__ flag,
    int* __restrict__ cnt, int* __restrict__ rank,
    const float* __restrict__ x, const f16* __restrict__ W1t,
    const float* __restrict__ b1, const f16* __restrict__ W2t,
    const float* __restrict__ b2, f16* __restrict__ h)
{
  __shared__ __align__(16) char smraw[2 * 64 * 136 * 2]; // 34816 B
  if (blockIdx.x >= MLP_BLKS) {
    int g = (blockIdx.x - MLP_BLKS) * 256 + threadIdx.x;
    int e0 = g * 4;
    if (e0 >= NE) return;
    int is64 = *flag;
    int d0, d1, d2, d3;
    if (is64) {
      int4 a = *(const int4*)&ei[2 * (size_t)NE + 2 * (size_t)e0];
      int4 b = *(const int4*)&ei[2 * (size_t)NE + 2 * (size_t)e0 + 4];
      d0 = a.x; d1 = a.z; d2 = b.x; d3 = b.z;
    } else {
      int4 a = *(const int4*)&ei[(size_t)NE + e0];
      d0 = a.x; d1 = a.y; d2 = a.z; d3 = a.w;
    }
    int4 rk;
    rk.x = atomicAdd(&cnt[d0], 1);
    rk.y = atomicAdd(&cnt[d1], 1);
    rk.z = atomicAdd(&cnt[d2], 1);
    rk.w = atomicAdd(&cnt[d3], 1);
    *(int4*)&rank[e0] = rk;
    return;
  }
  f16* xsb = (f16*)smraw;
  f16* h1s = (f16*)smraw;
  int t = threadIdx.x;
  int lane = t & 63;
  int w = t >> 6;
  int n0 = blockIdx.x * 64;
  int r15 = lane & 15;
  int g4 = lane >> 4;
  int nbase = w * 64;
  int srow = t >> 5, sc4 = t & 31;

  f32x4 acc[4][4];
  #pragma unroll
  for (int nt = 0; nt < 4; nt++) {
    float bv = b1[nbase + nt * 16 + r15];
    #pragma unroll
    for (int mt = 0; mt < 4; mt++) acc[mt][nt] = (f32x4){bv, bv, bv, bv};
  }

  float4 ld[8];
  #pragma unroll
  for (int it = 0; it < 8; it++) {
    int row = srow + it * 8;
    int gr = n0 + row;
    ld[it] = (gr < NN) ? *(const float4*)&x[(size_t)gr * DIN + sc4 * 4]
                       : make_float4(0.f, 0.f, 0.f, 0.f);
  }
  #pragma unroll
  for (int it = 0; it < 8; it++) {
    int row = srow + it * 8;
    f16x4 hv = { (f16)ld[it].x, (f16)ld[it].y, (f16)ld[it].z, (f16)ld[it].w };
    *(f16x4*)&xsb[row * 136 + sc4 * 4] = hv;
  }
  __syncthreads();

  for (int c = 0; c < 4; c++) {
    int cur = c & 1;
    if (c < 3) {
      #pragma unroll
      for (int it = 0; it < 8; it++) {
        int row = srow + it * 8;
        int gr = n0 + row;
        ld[it] = (gr < NN)
            ? *(const float4*)&x[(size_t)gr * DIN + (c + 1) * 128 + sc4 * 4]
            : make_float4(0.f, 0.f, 0.f, 0.f);
      }
    }
    int k0 = c * 128;
    const f16* xs = xsb + cur * 8704;
    #pragma unroll
    for (int ks = 0; ks < 4; ks++) {
      int kk = ks * 32 + g4 * 8;
      f16x8 a[4], b[4];
      #pragma unroll
      for (int mt = 0; mt < 4; mt++)
        a[mt] = *(const f16x8*)&xs[(mt * 16 + r15) * 136 + kk];
      #pragma unroll
      for (int nt = 0; nt < 4; nt++)
        b[nt] = *(const f16x8*)&W1t[(size_t)(nbase + nt * 16 + r15) * DIN + k0 + kk];
      #pragma unroll
      for (int mt = 0; mt < 4; mt++)
        #pragma unroll
        for (int nt = 0; nt < 4; nt++)
          acc[mt][nt] = __builtin_amdgcn_mfma_f32_16x16x32_f16(a[mt], b[nt], acc[mt][nt], 0, 0, 0);
    }
    if (c < 3) {
      #pragma unroll
      for (int it = 0; it < 8; it++) {
        int row = srow + it * 8;
        f16x4 hv = { (f16)ld[it].x, (f16)ld[it].y, (f16)ld[it].z, (f16)ld[it].w };
        *(f16x4*)&xsb[(cur ^ 1) * 8704 + row * 136 + sc4 * 4] = hv;
      }
    }
    __syncthreads();
  }

  #pragma unroll
  for (int mt = 0; mt < 4; mt++)
    #pragma unroll
    for (int nt = 0; nt < 4; nt++)
      #pragma unroll
      for (int r = 0; r < 4; r++) {
        float v = fmaxf(acc[mt][nt][r], 0.f);
        h1s[(mt * 16 + g4 * 4 + r) * 264 + nbase + nt * 16 + r15] = (f16)v;
      }
  __syncthreads();

  f32x4 acc2[4];
  #pragma unroll
  for (int nt = 0; nt < 4; nt++) {
    float bv = b2[nt * 16 + r15];
    acc2[nt] = (f32x4){bv, bv, bv, bv};
  }
  #pragma unroll
  for (int ks = 0; ks < 8; ks++) {
    int kk = ks * 32 + g4 * 8;
    f16x8 a2 = *(const f16x8*)&h1s[(w * 16 + r15) * 264 + kk];
    #pragma unroll
    for (int nt = 0; nt < 4; nt++) {
      f16x8 bf = *(const f16x8*)&W2t[(size_t)(nt * 16 + r15) * DHID + kk];
      acc2[nt] = __builtin_amdgcn_mfma_f32_16x16x32_f16(a2, bf, acc2[nt], 0, 0, 0);
    }
  }
  #pragma unroll
  for (int nt = 0; nt < 4; nt++)
    #pragma unroll
    for (int r = 0; r < 4; r++) {
      int node = n0 + w * 16 + g4 * 4 + r;
      if (node < NN)
        h[(size_t)node * DOUT + nt * 16 + r15] = (f16)acc2[nt][r];
    }
}

// ---------------- exclusive scan over cnt ----------------
__global__ void scan1(const int* __restrict__ cnt, int* __restrict__ rs,
                      int* __restrict__ bsum) {
  __shared__ int tmp[1024];
  int t = threadIdx.x;
  int g = blockIdx.x * 1024 + t;
  int v = (g < NN) ? cnt[g] : 0;
  tmp[t] = v;
  __syncthreads();
  for (int off = 1; off < 1024; off <<= 1) {
    int y = (t >= off) ? tmp[t - off] : 0;
    __syncthreads();
    tmp[t] += y;
    __syncthreads();
  }
  if (g < NN) rs[g] = tmp[t] - v;
  if (t == 1023) bsum[blockIdx.x] = tmp[t];
}

__global__ void scan2(int* __restrict__ bsum, int nb) {
  int lane = threadIdx.x;  // 64
  int v0 = (lane < nb) ? bsum[lane] : 0;
  int v1 = (64 + lane < nb) ? bsum[64 + lane] : 0;
  int s0 = v0, s1 = v1;
  for (int off = 1; off < 64; off <<= 1) {
    int t0 = __shfl_up(s0, off);
    int t1 = __shfl_up(s1, off);
    if (lane >= off) { s0 += t0; s1 += t1; }
  }
  int tot0 = __shfl(s0, 63);
  if (lane < nb) bsum[lane] = s0 - v0;
  if (64 + lane < nb) bsum[64 + lane] = tot0 + s1 - v1;
}

__global__ void scan3_and_dis(int* __restrict__ rs, const int* __restrict__ bsum,
                              const int* __restrict__ cnt, float* __restrict__ dis) {
  int g = blockIdx.x * blockDim.x + threadIdx.x;
  if (g < NN) {
    rs[g] = rs[g] + bsum[g >> 10];
    dis[g] = rsqrtf((float)(cnt[g] + 1));
  }
}

// ---------------- CSR fill (col-only, atomic-free) ----------------
__global__ void fill_csr(const int* __restrict__ ei, const int* __restrict__ flag,
                         const int* __restrict__ rs, const int* __restrict__ rank,
                         int* __restrict__ col) {
  int g = blockIdx.x * blockDim.x + threadIdx.x;
  int e0 = g * 4;
  if (e0 >= NE) return;
  int is64 = *flag;
  int s[4], d[4];
  if (is64) {
    int4 a = *(const int4*)&ei[2 * (size_t)NE + 2 * (size_t)e0];
    int4 b = *(const int4*)&ei[2 * (size_t)NE + 2 * (size_t)e0 + 4];
    d[0] = a.x; d[1] = a.z; d[2] = b.x; d[3] = b.z;
    int4 c = *(const int4*)&ei[2 * (size_t)e0];
    int4 e = *(const int4*)&ei[2 * (size_t)e0 + 4];
    s[0] = c.x; s[1] = c.z; s[2] = e.x; s[3] = e.z;
  } else {
    int4 a = *(const int4*)&ei[(size_t)NE + e0];
    d[0] = a.x; d[1] = a.y; d[2] = a.z; d[3] = a.w;
    int4 c = *(const int4*)&ei[e0];
    s[0] = c.x; s[1] = c.y; s[2] = c.z; s[3] = c.w;
  }
  int4 rk = *(const int4*)&rank[e0];
  int rka[4] = { rk.x, rk.y, rk.z, rk.w };
  #pragma unroll
  for (int j = 0; j < 4; j++)
    col[rs[d[j]] + rka[j]] = s[j];
}

// ---------------- zs seed (fallback path only) ----------------
__global__ void seed_zs(const float* __restrict__ dis, const float* __restrict__ temp,
                        const f16* __restrict__ h, f16* __restrict__ zs) {
  int g = blockIdx.x * 256 + threadIdx.x;
  int node = g >> 3;
  if (node < NN) {
    float dv = dis[node] * temp[KPROP];
    f16x8 hv = *(const f16x8*)&h[(size_t)g * 8];
    f16x8 o;
    #pragma unroll
    for (int f = 0; f < 8; f++) o[f] = (f16)(dv * (float)hv[f]);
    *(f16x8*)&zs[(size_t)g * 8] = o;
  }
}

// ---------------- prop node body (shared by coop + fallback) --------------
__device__ __forceinline__ void prop_node(
    int w, int lane, const f16* __restrict__ zs, f16* __restrict__ zsn,
    const f16* __restrict__ h, float* __restrict__ out,
    const int* __restrict__ rs, const int* __restrict__ cnt,
    const int* __restrict__ col, const float* __restrict__ dis,
    float gk, bool final_step)
{
  int q = lane >> 3;
  int s8 = lane & 7;

  float dd = dis[w];
  f16x8 zself = *(const f16x8*)&zs[(size_t)w * DOUT + s8 * 8];
  f16x8 hs = *(const f16x8*)&h[(size_t)w * DOUT + s8 * 8];

  float acc[8];
  #pragma unroll
  for (int f = 0; f < 8; f++) acc[f] = 0.f;

  int beg = rs[w], n = cnt[w];
  const int* cp = col + beg;

  int e = 0;
  for (; e + 32 <= n; e += 32) {
    int c0 = cp[e + q];
    int c1 = cp[e + 8 + q];
    int c2 = cp[e + 16 + q];
    int c3 = cp[e + 24 + q];
    f16x8 g0 = *(const f16x8*)&zs[(size_t)c0 * DOUT + s8 * 8];
    f16x8 g1 = *(const f16x8*)&zs[(size_t)c1 * DOUT + s8 * 8];
    f16x8 g2 = *(const f16x8*)&zs[(size_t)c2 * DOUT + s8 * 8];
    f16x8 g3 = *(const f16x8*)&zs[(size_t)c3 * DOUT + s8 * 8];
    #pragma unroll
    for (int f = 0; f < 8; f++) acc[f] += (float)g0[f];
    #pragma unroll
    for (int f = 0; f < 8; f++) acc[f] += (float)g1[f];
    #pragma unroll
    for (int f = 0; f < 8; f++) acc[f] += (float)g2[f];
    #pragma unroll
    for (int f = 0; f < 8; f++) acc[f] += (float)g3[f];
  }
  for (; e + 8 <= n; e += 8) {
    int c0 = cp[e + q];
    f16x8 g0 = *(const f16x8*)&zs[(size_t)c0 * DOUT + s8 * 8];
    #pragma unroll
    for (int f = 0; f < 8; f++) acc[f] += (float)g0[f];
  }
  if (e < n) {
    int rem = n - e;
    int qq = q < rem ? q : rem - 1;
    int c0 = cp[e + qq];
    f16x8 g0 = *(const f16x8*)&zs[(size_t)c0 * DOUT + s8 * 8];
    float m = (q < rem) ? 1.f : 0.f;
    #pragma unroll
    for (int f = 0; f < 8; f++) acc[f] = fmaf(m, (float)g0[f], acc[f]);
  }

  #pragma unroll
  for (int f = 0; f < 8; f++) {
    acc[f] += __shfl_xor(acc[f], 8);
    acc[f] += __shfl_xor(acc[f], 16);
    acc[f] += __shfl_xor(acc[f], 32);
  }

  if (q == 0) {
    float zv[8];
    #pragma unroll
    for (int f = 0; f < 8; f++)
      zv[f] = gk * (float)hs[f] + dd * (acc[f] + (float)zself[f]);
    if (final_step) {
      float4 o0 = { zv[0], zv[1], zv[2], zv[3] };
      float4 o1 = { zv[4], zv[5], zv[6], zv[7] };
      *(float4*)&out[(size_t)w * DOUT + s8 * 8] = o0;
      *(float4*)&out[(size_t)w * DOUT + s8 * 8 + 4] = o1;
    } else {
      f16x8 o;
      #pragma unroll
      for (int f = 0; f < 8; f++) o[f] = (f16)(dd * zv[f]);
      *(f16x8*)&zsn[(size_t)w * DOUT + s8 * 8] = o;
    }
  }
}

// ---------------- persistent cooperative prop: seed + 10 steps ------------
// 1536 blocks (6/CU co-resident), grid.sync between K-steps. Eliminates 9
// launch gaps + 9 residency-wave tails vs 10 separate launches, and absorbs
// the zs seed. __threadfence() before sync for cross-XCD visibility (G16).
__global__ __launch_bounds__(256, 6) void prop_persist(
    f16* __restrict__ zs_a, f16* __restrict__ zs_b, const f16* __restrict__ h,
    float* __restrict__ out, const int* __restrict__ rs, const int* __restrict__ cnt,
    const int* __restrict__ col, const float* __restrict__ dis,
    const float* __restrict__ temp)
{
  cg::grid_group grid = cg::this_grid();
  int wave = threadIdx.x >> 6, lane = threadIdx.x & 63;

  // seed: zs_a = dis * temp[K] * h
  float tK = temp[KPROP];
  for (int i = blockIdx.x * 256 + threadIdx.x; i < NN * 8; i += PROP_BLKS * 256) {
    int node = i >> 3;
    float dv = dis[node] * tK;
    f16x8 hv = *(const f16x8*)&h[(size_t)i * 8];
    f16x8 o;
    #pragma unroll
    for (int f = 0; f < 8; f++) o[f] = (f16)(dv * (float)hv[f]);
    *(f16x8*)&zs_a[(size_t)i * 8] = o;
  }
  __threadfence();
  grid.sync();

  const f16* zc = zs_a;
  f16* zn = zs_b;
  for (int k = KPROP - 1; k >= 0; k--) {
    float gk = temp[k];
    bool fin = (k == 0);
    for (int c = 0; c < NCHUNK; c++) {
      int w = (c * PROP_BLKS + blockIdx.x) * 4 + wave;
      if (w < NN)
        prop_node(w, lane, zc, zn, h, out, rs, cnt, col, dis, gk, fin);
    }
    __threadfence();
    grid.sync();
    const f16* t2 = zn;
    zn = (f16*)zc;
    zc = t2;
  }
}

// ---------------- fallback single-step prop (r17/r18 measured-good) -------
__global__ __launch_bounds__(256) void prop_horner(
    const f16* __restrict__ zs, f16* __restrict__ zsn, const f16* __restrict__ h,
    float* __restrict__ out, const int* __restrict__ rs, const int* __restrict__ cnt,
    const int* __restrict__ col, const float* __restrict__ dis,
    const float* __restrict__ temp, int kidx, int final_step)
{
  int w = blockIdx.x * 4 + (threadIdx.x >> 6);
  int lane = threadIdx.x & 63;
  if (w >= NN) return;
  prop_node(w, lane, zs, zsn, h, out, rs, cnt, col, dis, temp[kidx],
            final_step != 0);
}

// ---------------- launch ----------------
extern "C" void kernel_launch(void* const* d_in, const int* in_sizes, int n_in,
                              void* d_out, int out_size, void* d_ws, size_t ws_size,
                              hipStream_t stream) {
  const float* x    = (const float*)d_in[0];
  const int*   ei   = (const int*)d_in[1];
  const float* W1   = (const float*)d_in[2];
  const float* b1   = (const float*)d_in[3];
  const float* W2   = (const float*)d_in[4];
  const float* b2   = (const float*)d_in[5];
  const float* temp = (const float*)d_in[6];
  float* out = (float*)d_out;

  char* wsb = (char*)d_ws;
  size_t off = 0;
  auto carve = [&](size_t bytes) -> void* {
    void* p = wsb + off;
    off = (off + bytes + 255) & ~(size_t)255;
    return p;
  };
  int*   cnt    = (int*)carve((size_t)NN * 4);
  int*   rs     = (int*)carve((size_t)NN * 4);
  int*   bsum   = (int*)carve(128 * 4);
  int*   flag   = (int*)carve(256);
  float* dis    = (float*)carve((size_t)NN * 4);
  int*   rank   = (int*)carve((size_t)NE * 4);   // 12.8 MB
  int*   colA   = (int*)carve((size_t)NE * 4);   // 12.8 MB
  f16*   W1t    = (f16*)carve((size_t)DHID * DIN * 2);
  f16*   W2t    = (f16*)carve((size_t)DOUT * DHID * 2);
  f16*   h_buf  = (f16*)carve((size_t)NN * DOUT * 2);
  f16*   zs_a   = (f16*)carve((size_t)NN * DOUT * 2);
  f16*   zs_b   = (f16*)carve((size_t)NN * DOUT * 2);
  if (off > ws_size) return; // ~66 MB needed

  zero_detect<<<(NN + 255) / 256, 256, 0, stream>>>(cnt, ei, flag);
  cvt_weights<<<(DIN * DHID + 255) / 256, 256, 0, stream>>>(W1, W2, W1t, W2t);
  count_mlp<<<MLP_BLKS + CNT_BLKS, 256, 0, stream>>>(ei, flag, cnt, rank,
                                                     x, W1t, b1, W2t, b2, h_buf);
  scan1<<<(NN + 1023) / 1024, 1024, 0, stream>>>(cnt, rs, bsum);
  scan2<<<1, 64, 0, stream>>>(bsum, (NN + 1023) / 1024);
  scan3_and_dis<<<(NN + 255) / 256, 256, 0, stream>>>(rs, bsum, cnt, dis);
  fill_csr<<<FILL_BLKS, 256, 0, stream>>>(ei, flag, rs, rank, colA);

  void* args[] = { (void*)&zs_a, (void*)&zs_b, (void*)&h_buf, (void*)&out,
                   (void*)&rs, (void*)&cnt, (void*)&colA, (void*)&dis,
                   (void*)&temp };
  hipError_t err = hipLaunchCooperativeKernel((void*)prop_persist,
                                              dim3(PROP_BLKS), dim3(256),
                                              args, 0, stream);
  if (err != hipSuccess) {
    // fallback: r18 measured-good path (seed + 10 launches)
    seed_zs<<<3125, 256, 0, stream>>>(dis, temp, h_buf, zs_a);
    const f16* zc = zs_a;
    f16* zn = zs_b;
    for (int k = KPROP - 1; k >= 0; k--) {
      prop_horner<<<(NN + 3) / 4, 256, 0, stream>>>(zc, zn, h_buf, out, rs, cnt,
                                                    colA, dis, temp, k, k == 0);
      const f16* t2 = zn;
      zn = (f16*)zc;
      zc = t2;
    }
  }
}

// Round 20
// 865.904 us; speedup vs baseline: 5.5770x; 5.5770x over previous
//
#include <hip/hip_runtime.h>

#define NN 100000
#define NE 3200000
#define DIN 512
#define DHID 256
#define DOUT 64
#define KPROP 10
#define MLP_BLKS ((NN + 63) / 64)        // 1563
#define CNT_BLKS ((NE / 4 + 255) / 256)  // 3125
#define FILL_BLKS ((NE / 4 + 255) / 256) // 3125
#define SEED_BLKS 3125                   // 100000*64/2048 f16 elems

typedef _Float16 f16;
typedef _Float16 f16x8 __attribute__((ext_vector_type(8)));
typedef _Float16 f16x4 __attribute__((ext_vector_type(4)));
typedef float f32x4 __attribute__((ext_vector_type(4)));

// ---------------- zero + edge-layout probe (fused) ----------------
__global__ void zero_detect(int* __restrict__ cnt, const int* __restrict__ ei,
                            int* __restrict__ flag) {
  int g = blockIdx.x * blockDim.x + threadIdx.x;
  if (g < NN) cnt[g] = 0;
  if (blockIdx.x == 0 && threadIdx.x < 64) {
    int lane = threadIdx.x;
    int ok = 1;
    for (int i = lane; i < 512; i += 64)
      if (ei[2 * i + 1] != 0) ok = 0;
    ok = __all(ok);
    if (lane == 0) *flag = ok;
  }
}

// ---------------- weight transpose + fp16 convert ----------------
__global__ void cvt_weights(const float* __restrict__ W1, const float* __restrict__ W2,
                            f16* __restrict__ W1t, f16* __restrict__ W2t) {
  int g = blockIdx.x * 256 + threadIdx.x;
  if (g < DIN * DHID) {
    int k = g >> 8, n = g & 255;
    W1t[(size_t)n * DIN + k] = (f16)W1[g];
  }
  if (g < DHID * DOUT) {
    int k = g >> 6, n = g & 63;
    W2t[(size_t)n * DHID + k] = (f16)W2[g];
  }
}

// ---------------- FUSED: mlp (blocks 0..1562) + count_deg (rest) ---------
// r18 measured: 250us vs 288 sequential — atomic-unit-bound count overlaps
// latency-bound mlp (disjoint resources). r19's cooperative persistent prop
// was 9x WORSE (grid.sync destroys the L2/L3-resident regime via cross-XCD
// coherence flush) — launch-per-step is the measured-best structure.
__global__ __launch_bounds__(256) void count_mlp(
    const int* __restrict__ ei, const int* __restrict__ flag,
    int* __restrict__ cnt, int* __restrict__ rank,
    const float* __restrict__ x, const f16* __restrict__ W1t,
    const float* __restrict__ b1, const f16* __restrict__ W2t,
    const float* __restrict__ b2, f16* __restrict__ h)
{
  __shared__ __align__(16) char smraw[2 * 64 * 136 * 2]; // 34816 B
  if (blockIdx.x >= MLP_BLKS) {
    int g = (blockIdx.x - MLP_BLKS) * 256 + threadIdx.x;
    int e0 = g * 4;
    if (e0 >= NE) return;
    int is64 = *flag;
    int d0, d1, d2, d3;
    if (is64) {
      int4 a = *(const int4*)&ei[2 * (size_t)NE + 2 * (size_t)e0];
      int4 b = *(const int4*)&ei[2 * (size_t)NE + 2 * (size_t)e0 + 4];
      d0 = a.x; d1 = a.z; d2 = b.x; d3 = b.z;
    } else {
      int4 a = *(const int4*)&ei[(size_t)NE + e0];
      d0 = a.x; d1 = a.y; d2 = a.z; d3 = a.w;
    }
    int4 rk;
    rk.x = atomicAdd(&cnt[d0], 1);
    rk.y = atomicAdd(&cnt[d1], 1);
    rk.z = atomicAdd(&cnt[d2], 1);
    rk.w = atomicAdd(&cnt[d3], 1);
    *(int4*)&rank[e0] = rk;
    return;
  }
  f16* xsb = (f16*)smraw;          // xs[buf][row][136]
  f16* h1s = (f16*)smraw;          // h1s[row][264] (aliased; disjoint lifetime)
  int t = threadIdx.x;
  int lane = t & 63;
  int w = t >> 6;
  int n0 = blockIdx.x * 64;
  int r15 = lane & 15;
  int g4 = lane >> 4;
  int nbase = w * 64;
  int srow = t >> 5, sc4 = t & 31;

  f32x4 acc[4][4];
  #pragma unroll
  for (int nt = 0; nt < 4; nt++) {
    float bv = b1[nbase + nt * 16 + r15];
    #pragma unroll
    for (int mt = 0; mt < 4; mt++) acc[mt][nt] = (f32x4){bv, bv, bv, bv};
  }

  float4 ld[8];
  #pragma unroll
  for (int it = 0; it < 8; it++) {
    int row = srow + it * 8;
    int gr = n0 + row;
    ld[it] = (gr < NN) ? *(const float4*)&x[(size_t)gr * DIN + sc4 * 4]
                       : make_float4(0.f, 0.f, 0.f, 0.f);
  }
  #pragma unroll
  for (int it = 0; it < 8; it++) {
    int row = srow + it * 8;
    f16x4 hv = { (f16)ld[it].x, (f16)ld[it].y, (f16)ld[it].z, (f16)ld[it].w };
    *(f16x4*)&xsb[row * 136 + sc4 * 4] = hv;
  }
  __syncthreads();

  for (int c = 0; c < 4; c++) {
    int cur = c & 1;
    if (c < 3) {
      #pragma unroll
      for (int it = 0; it < 8; it++) {
        int row = srow + it * 8;
        int gr = n0 + row;
        ld[it] = (gr < NN)
            ? *(const float4*)&x[(size_t)gr * DIN + (c + 1) * 128 + sc4 * 4]
            : make_float4(0.f, 0.f, 0.f, 0.f);
      }
    }
    int k0 = c * 128;
    const f16* xs = xsb + cur * 8704;
    #pragma unroll
    for (int ks = 0; ks < 4; ks++) {
      int kk = ks * 32 + g4 * 8;
      f16x8 a[4], b[4];
      #pragma unroll
      for (int mt = 0; mt < 4; mt++)
        a[mt] = *(const f16x8*)&xs[(mt * 16 + r15) * 136 + kk];
      #pragma unroll
      for (int nt = 0; nt < 4; nt++)
        b[nt] = *(const f16x8*)&W1t[(size_t)(nbase + nt * 16 + r15) * DIN + k0 + kk];
      #pragma unroll
      for (int mt = 0; mt < 4; mt++)
        #pragma unroll
        for (int nt = 0; nt < 4; nt++)
          acc[mt][nt] = __builtin_amdgcn_mfma_f32_16x16x32_f16(a[mt], b[nt], acc[mt][nt], 0, 0, 0);
    }
    if (c < 3) {
      #pragma unroll
      for (int it = 0; it < 8; it++) {
        int row = srow + it * 8;
        f16x4 hv = { (f16)ld[it].x, (f16)ld[it].y, (f16)ld[it].z, (f16)ld[it].w };
        *(f16x4*)&xsb[(cur ^ 1) * 8704 + row * 136 + sc4 * 4] = hv;
      }
    }
    __syncthreads();
  }

  // relu -> h1s (D layout: col = lane&15, row = g4*4+reg [m89-verified])
  #pragma unroll
  for (int mt = 0; mt < 4; mt++)
    #pragma unroll
    for (int nt = 0; nt < 4; nt++)
      #pragma unroll
      for (int r = 0; r < 4; r++) {
        float v = fmaxf(acc[mt][nt][r], 0.f);
        h1s[(mt * 16 + g4 * 4 + r) * 264 + nbase + nt * 16 + r15] = (f16)v;
      }
  __syncthreads();

  f32x4 acc2[4];
  #pragma unroll
  for (int nt = 0; nt < 4; nt++) {
    float bv = b2[nt * 16 + r15];
    acc2[nt] = (f32x4){bv, bv, bv, bv};
  }
  #pragma unroll
  for (int ks = 0; ks < 8; ks++) {
    int kk = ks * 32 + g4 * 8;
    f16x8 a2 = *(const f16x8*)&h1s[(w * 16 + r15) * 264 + kk];
    #pragma unroll
    for (int nt = 0; nt < 4; nt++) {
      f16x8 bf = *(const f16x8*)&W2t[(size_t)(nt * 16 + r15) * DHID + kk];
      acc2[nt] = __builtin_amdgcn_mfma_f32_16x16x32_f16(a2, bf, acc2[nt], 0, 0, 0);
    }
  }
  #pragma unroll
  for (int nt = 0; nt < 4; nt++)
    #pragma unroll
    for (int r = 0; r < 4; r++) {
      int node = n0 + w * 16 + g4 * 4 + r;
      if (node < NN)
        h[(size_t)node * DOUT + nt * 16 + r15] = (f16)acc2[nt][r];
    }
}

// ---------------- exclusive scan over cnt ----------------
__global__ void scan1(const int* __restrict__ cnt, int* __restrict__ rs,
                      int* __restrict__ bsum) {
  __shared__ int tmp[1024];
  int t = threadIdx.x;
  int g = blockIdx.x * 1024 + t;
  int v = (g < NN) ? cnt[g] : 0;
  tmp[t] = v;
  __syncthreads();
  for (int off = 1; off < 1024; off <<= 1) {
    int y = (t >= off) ? tmp[t - off] : 0;
    __syncthreads();
    tmp[t] += y;
    __syncthreads();
  }
  if (g < NN) rs[g] = tmp[t] - v;           // exclusive
  if (t == 1023) bsum[blockIdx.x] = tmp[t]; // block total
}

// wave-parallel scan of <=128 block sums
__global__ void scan2(int* __restrict__ bsum, int nb) {
  int lane = threadIdx.x;  // 64
  int v0 = (lane < nb) ? bsum[lane] : 0;
  int v1 = (64 + lane < nb) ? bsum[64 + lane] : 0;
  int s0 = v0, s1 = v1;
  for (int off = 1; off < 64; off <<= 1) {
    int t0 = __shfl_up(s0, off);
    int t1 = __shfl_up(s1, off);
    if (lane >= off) { s0 += t0; s1 += t1; }
  }
  int tot0 = __shfl(s0, 63);
  if (lane < nb) bsum[lane] = s0 - v0;                 // exclusive
  if (64 + lane < nb) bsum[64 + lane] = tot0 + s1 - v1;
}

__global__ void scan3_and_dis(int* __restrict__ rs, const int* __restrict__ bsum,
                              const int* __restrict__ cnt, float* __restrict__ dis) {
  int g = blockIdx.x * blockDim.x + threadIdx.x;
  if (g < NN) {
    rs[g] = rs[g] + bsum[g >> 10];
    dis[g] = rsqrtf((float)(cnt[g] + 1)); // +1 self-loop
  }
}

// ---------------- FUSED: CSR fill (col-only, atomic-free) + zs seed -------
__global__ void fill_seed(const int* __restrict__ ei, const int* __restrict__ flag,
                          const int* __restrict__ rs, const int* __restrict__ rank,
                          int* __restrict__ col, const float* __restrict__ dis,
                          const float* __restrict__ temp, const f16* __restrict__ h,
                          f16* __restrict__ zs) {
  if (blockIdx.x >= FILL_BLKS) {
    // zs = dis * temp[K] * h (scaled-z Horner seed), 8 f16 per thread
    int g = (blockIdx.x - FILL_BLKS) * 256 + threadIdx.x;
    int node = g >> 3;
    if (node < NN) {
      float dv = dis[node] * temp[KPROP];
      f16x8 hv = *(const f16x8*)&h[(size_t)g * 8];
      f16x8 o;
      #pragma unroll
      for (int f = 0; f < 8; f++) o[f] = (f16)(dv * (float)hv[f]);
      *(f16x8*)&zs[(size_t)g * 8] = o;
    }
    return;
  }
  int g = blockIdx.x * blockDim.x + threadIdx.x;
  int e0 = g * 4;
  if (e0 >= NE) return;
  int is64 = *flag;
  int s[4], d[4];
  if (is64) {
    int4 a = *(const int4*)&ei[2 * (size_t)NE + 2 * (size_t)e0];
    int4 b = *(const int4*)&ei[2 * (size_t)NE + 2 * (size_t)e0 + 4];
    d[0] = a.x; d[1] = a.z; d[2] = b.x; d[3] = b.z;
    int4 c = *(const int4*)&ei[2 * (size_t)e0];
    int4 e = *(const int4*)&ei[2 * (size_t)e0 + 4];
    s[0] = c.x; s[1] = c.z; s[2] = e.x; s[3] = e.z;
  } else {
    int4 a = *(const int4*)&ei[(size_t)NE + e0];
    d[0] = a.x; d[1] = a.y; d[2] = a.z; d[3] = a.w;
    int4 c = *(const int4*)&ei[e0];
    s[0] = c.x; s[1] = c.y; s[2] = c.z; s[3] = c.w;
  }
  int4 rk = *(const int4*)&rank[e0];
  int rka[4] = { rk.x, rk.y, rk.z, rk.w };
  #pragma unroll
  for (int j = 0; j < 4; j++)
    col[rs[d[j]] + rka[j]] = s[j];
}

// ---------------- scaled-z Horner prop (r17/r18 measured-best) ------------
// zs = dis * z. (A_hat z)[d] = dis[d]*(sum_{s in N(d)} zs[s] + zs[d]) —
// unweighted gather-sum, col-only 4B records. One launch per K-step (r19:
// cooperative persistent version was 9x slower — cache-regime destruction).
__global__ __launch_bounds__(256) void prop_horner(
    const f16* __restrict__ zs, f16* __restrict__ zsn, const f16* __restrict__ h,
    float* __restrict__ out, const int* __restrict__ rs, const int* __restrict__ cnt,
    const int* __restrict__ col, const float* __restrict__ dis,
    const float* __restrict__ temp, int kidx, int final_step)
{
  int w = blockIdx.x * 4 + (threadIdx.x >> 6);
  int lane = threadIdx.x & 63;
  if (w >= NN) return;
  int q = lane >> 3;
  int s8 = lane & 7;

  float dd = dis[w];
  float gk = temp[kidx];
  f16x8 zself = *(const f16x8*)&zs[(size_t)w * DOUT + s8 * 8];
  f16x8 hs = *(const f16x8*)&h[(size_t)w * DOUT + s8 * 8];

  float acc[8];
  #pragma unroll
  for (int f = 0; f < 8; f++) acc[f] = 0.f;

  int beg = rs[w], n = cnt[w];
  const int* cp = col + beg;

  int e = 0;
  for (; e + 32 <= n; e += 32) {
    int c0 = cp[e + q];
    int c1 = cp[e + 8 + q];
    int c2 = cp[e + 16 + q];
    int c3 = cp[e + 24 + q];
    f16x8 g0 = *(const f16x8*)&zs[(size_t)c0 * DOUT + s8 * 8];
    f16x8 g1 = *(const f16x8*)&zs[(size_t)c1 * DOUT + s8 * 8];
    f16x8 g2 = *(const f16x8*)&zs[(size_t)c2 * DOUT + s8 * 8];
    f16x8 g3 = *(const f16x8*)&zs[(size_t)c3 * DOUT + s8 * 8];
    #pragma unroll
    for (int f = 0; f < 8; f++) acc[f] += (float)g0[f];
    #pragma unroll
    for (int f = 0; f < 8; f++) acc[f] += (float)g1[f];
    #pragma unroll
    for (int f = 0; f < 8; f++) acc[f] += (float)g2[f];
    #pragma unroll
    for (int f = 0; f < 8; f++) acc[f] += (float)g3[f];
  }
  for (; e + 8 <= n; e += 8) {
    int c0 = cp[e + q];
    f16x8 g0 = *(const f16x8*)&zs[(size_t)c0 * DOUT + s8 * 8];
    #pragma unroll
    for (int f = 0; f < 8; f++) acc[f] += (float)g0[f];
  }
  if (e < n) {
    int rem = n - e;
    int qq = q < rem ? q : rem - 1;   // clamp; invalid slots masked to 0
    int c0 = cp[e + qq];
    f16x8 g0 = *(const f16x8*)&zs[(size_t)c0 * DOUT + s8 * 8];
    float m = (q < rem) ? 1.f : 0.f;
    #pragma unroll
    for (int f = 0; f < 8; f++) acc[f] = fmaf(m, (float)g0[f], acc[f]);
  }

  #pragma unroll
  for (int f = 0; f < 8; f++) {
    acc[f] += __shfl_xor(acc[f], 8);
    acc[f] += __shfl_xor(acc[f], 16);
    acc[f] += __shfl_xor(acc[f], 32);
  }

  if (q == 0) {
    float zv[8];
    #pragma unroll
    for (int f = 0; f < 8; f++)
      zv[f] = gk * (float)hs[f] + dd * (acc[f] + (float)zself[f]);
    if (final_step) {
      float4 o0 = { zv[0], zv[1], zv[2], zv[3] };
      float4 o1 = { zv[4], zv[5], zv[6], zv[7] };
      *(float4*)&out[(size_t)w * DOUT + s8 * 8] = o0;
      *(float4*)&out[(size_t)w * DOUT + s8 * 8 + 4] = o1;
    } else {
      f16x8 o;
      #pragma unroll
      for (int f = 0; f < 8; f++) o[f] = (f16)(dd * zv[f]);
      *(f16x8*)&zsn[(size_t)w * DOUT + s8 * 8] = o;
    }
  }
}

// ---------------- launch ----------------
extern "C" void kernel_launch(void* const* d_in, const int* in_sizes, int n_in,
                              void* d_out, int out_size, void* d_ws, size_t ws_size,
                              hipStream_t stream) {
  const float* x    = (const float*)d_in[0];
  const int*   ei   = (const int*)d_in[1];
  const float* W1   = (const float*)d_in[2];
  const float* b1   = (const float*)d_in[3];
  const float* W2   = (const float*)d_in[4];
  const float* b2   = (const float*)d_in[5];
  const float* temp = (const float*)d_in[6];
  float* out = (float*)d_out;

  char* wsb = (char*)d_ws;
  size_t off = 0;
  auto carve = [&](size_t bytes) -> void* {
    void* p = wsb + off;
    off = (off + bytes + 255) & ~(size_t)255;
    return p;
  };
  int*   cnt    = (int*)carve((size_t)NN * 4);
  int*   rs     = (int*)carve((size_t)NN * 4);
  int*   bsum   = (int*)carve(128 * 4);
  int*   flag   = (int*)carve(256);
  float* dis    = (float*)carve((size_t)NN * 4);
  int*   rank   = (int*)carve((size_t)NE * 4);   // 12.8 MB
  int*   colA   = (int*)carve((size_t)NE * 4);   // 12.8 MB
  f16*   W1t    = (f16*)carve((size_t)DHID * DIN * 2);
  f16*   W2t    = (f16*)carve((size_t)DOUT * DHID * 2);
  f16*   h_buf  = (f16*)carve((size_t)NN * DOUT * 2);
  f16*   zs_a   = (f16*)carve((size_t)NN * DOUT * 2);
  f16*   zs_b   = (f16*)carve((size_t)NN * DOUT * 2);
  if (off > ws_size) return; // ~66 MB needed

  zero_detect<<<(NN + 255) / 256, 256, 0, stream>>>(cnt, ei, flag);
  cvt_weights<<<(DIN * DHID + 255) / 256, 256, 0, stream>>>(W1, W2, W1t, W2t);
  count_mlp<<<MLP_BLKS + CNT_BLKS, 256, 0, stream>>>(ei, flag, cnt, rank,
                                                     x, W1t, b1, W2t, b2, h_buf);
  scan1<<<(NN + 1023) / 1024, 1024, 0, stream>>>(cnt, rs, bsum);
  scan2<<<1, 64, 0, stream>>>(bsum, (NN + 1023) / 1024);
  scan3_and_dis<<<(NN + 255) / 256, 256, 0, stream>>>(rs, bsum, cnt, dis);
  fill_seed<<<FILL_BLKS + SEED_BLKS, 256, 0, stream>>>(ei, flag, rs, rank, colA,
                                                       dis, temp, h_buf, zs_a);

  const f16* zc = zs_a;
  f16* zn = zs_b;
  for (int k = KPROP - 1; k >= 0; k--) {
    prop_horner<<<(NN + 3) / 4, 256, 0, stream>>>(zc, zn, h_buf, out, rs, cnt,
                                                  colA, dis, temp, k, k == 0);
    const f16* t2 = zn;
    zn = (f16*)zc;
    zc = t2;
  }
}